// Round 15
// baseline (1037.933 us; speedup 1.0000x reference)
//
#include <hip/hip_runtime.h>
#include <hip/hip_bf16.h>
#include <hip/hip_cooperative_groups.h>

namespace cg = cooperative_groups;

// ---------------------------------------------------------------------------
// GAT x3 + fc + MLP. R25 = R24 (469.4us) with the ENTIRE 10-dispatch preamble
// (CSR build x7 + conversions x3, ~110us incl. launch gaps) collapsed into
// ONE cooperative kernel (grid 1024x256, 5 grid.sync phases):
//   P0: zero counts/cursor | x/rc pad-convert | 7 weight transposes | flag
//   P1: edge convert + degree count     P2: chunk scans
//   P3: block-sums scan (1 block)       P4: row_ptr add      P5: edge_fill
// Hot kernels (gemm_gat+aux front-placed, gat_agg roofline form, fc)
// unchanged from R24.
// ---------------------------------------------------------------------------

#define GAT_SLOPE 0.2f
#define ACT_SLOPE 0.01f

typedef unsigned short ushort_t;
typedef __attribute__((ext_vector_type(8))) short bf16x8;
typedef __attribute__((ext_vector_type(8))) unsigned short ushort8v;
typedef __attribute__((ext_vector_type(4))) float floatx4;

__device__ __forceinline__ float lrelu(float x, float s) {
    return fmaxf(x, s * x);   // valid for 0<s<1
}

__device__ __forceinline__ ushort_t f2bf(float f) {
    union { float f; unsigned u; } x; x.f = f;
    unsigned r = x.u + 0x7FFF + ((x.u >> 16) & 1);   // round-nearest-even
    return (ushort_t)(r >> 16);
}

__device__ __forceinline__ float bf2f(ushort_t u) {
    union { unsigned u; float f; } x; x.u = ((unsigned)u) << 16;
    return x.f;
}

// ---------------- single cooperative preamble kernel ----------------
struct WConv { const float* in; ushort_t* out; int Kp, Kr, N, Npad; };

struct PreArgs {
    const int* rawEdge;
    int E, N, R;
    int* flag;
    int* idx32;      // [2E]
    int* counts;
    int* cursor;
    int* row_ptr;    // [N+1]
    int* incArr;
    int* blockSums;  // [512]
    int* colArr;
    const float* x;  ushort_t* x_bf;    // N x 96 (pad from 80)
    const float* rc; ushort_t* rc_bf;   // R x 64 (pad from 60)
    WConv w[7];
};

__global__ void preamble_all(PreArgs a) {
    cg::grid_group grid = cg::this_grid();
    const int tid  = blockIdx.x * blockDim.x + threadIdx.x;
    const int nthr = gridDim.x * blockDim.x;
    __shared__ int sh[256];

    // ---- P0: zeros + conversions + format flag (all independent) ----
    for (int i = tid; i < a.N; i += nthr) { a.counts[i] = 0; a.cursor[i] = 0; }
    {
        int tot = a.N * 96;
        for (int i = tid; i < tot; i += nthr) {
            int r = i / 96, c = i - r * 96;
            a.x_bf[i] = f2bf((c < 80) ? a.x[(size_t)r * 80 + c] : 0.f);
        }
    }
    {
        int tot = a.R * 64;
        for (int i = tid; i < tot; i += nthr) {
            int r = i / 64, c = i - r * 64;
            a.rc_bf[i] = f2bf((c < 60) ? a.rc[(size_t)r * 60 + c] : 0.f);
        }
    }
    for (int e = 0; e < 7; e++) {
        WConv w = a.w[e];
        int tot = w.Npad * w.Kp;
        for (int i = tid; i < tot; i += nthr) {
            int n = i / w.Kp, k = i - n * w.Kp;
            float v = (n < w.N && k < w.Kr) ? w.in[(size_t)k * w.N + n] : 0.f;
            w.out[i] = f2bf(v);
        }
    }
    if (blockIdx.x == 0) {
        __shared__ int nz;
        if (threadIdx.x == 0) nz = 0;
        __syncthreads();
        int lim = 2 * a.E < 4096 ? 2 * a.E : 4096;
        for (int i = threadIdx.x * 2 + 1; i < lim; i += 512)
            if (a.rawEdge[i] != 0) atomicAdd(&nz, 1);
        __syncthreads();
        if (threadIdx.x == 0) *a.flag = (nz == 0) ? 1 : 0;   // 1 => int64
    }
    grid.sync();

    // ---- P1: edge convert + degree count ----
    {
        int fmt = *a.flag;
        for (int i = tid; i < a.E; i += nthr) {
            int s = fmt ? a.rawEdge[2 * i] : a.rawEdge[i];
            int d = fmt ? a.rawEdge[2 * (a.E + i)] : a.rawEdge[a.E + i];
            a.idx32[i] = s;
            a.idx32[a.E + i] = d;
            atomicAdd(&a.counts[d], 1);
        }
    }
    grid.sync();

    // ---- P2: per-chunk (256-wide) inclusive scans ----
    const int nb = (a.N + 255) / 256;
    for (int ch = blockIdx.x; ch < nb; ch += gridDim.x) {
        int i = ch * 256 + threadIdx.x;
        int v = (i < a.N) ? a.counts[i] : 0;
        sh[threadIdx.x] = v;
        __syncthreads();
        for (int off = 1; off < 256; off <<= 1) {
            int t2 = (threadIdx.x >= off) ? sh[threadIdx.x - off] : 0;
            __syncthreads();
            sh[threadIdx.x] += t2;
            __syncthreads();
        }
        if (i < a.N) a.incArr[i] = sh[threadIdx.x];
        if (threadIdx.x == 255) a.blockSums[ch] = sh[255];
        __syncthreads();
    }
    grid.sync();

    // ---- P3: scan blockSums (single block, 256-wide with carry) ----
    if (blockIdx.x == 0) {
        int carry = 0;
        for (int base = 0; base < nb; base += 256) {
            int idx = base + threadIdx.x;
            int v = (idx < nb) ? a.blockSums[idx] : 0;
            sh[threadIdx.x] = v;
            __syncthreads();
            for (int off = 1; off < 256; off <<= 1) {
                int t2 = (threadIdx.x >= off) ? sh[threadIdx.x - off] : 0;
                __syncthreads();
                sh[threadIdx.x] += t2;
                __syncthreads();
            }
            if (idx < nb) a.blockSums[idx] = sh[threadIdx.x] + carry;
            int chunkTot = sh[255];
            __syncthreads();
            carry += chunkTot;
        }
    }
    grid.sync();

    // ---- P4: row_ptr[i+1] = inc[i] + prefix of previous chunks ----
    for (int i = tid; i < a.N; i += nthr) {
        int ch = i >> 8;
        a.row_ptr[i + 1] = a.incArr[i] + (ch > 0 ? a.blockSums[ch - 1] : 0);
    }
    if (tid == 0) a.row_ptr[0] = 0;
    grid.sync();

    // ---- P5: edge fill ----
    for (int i = tid; i < a.E; i += nthr) {
        int d = a.idx32[a.E + i];
        int pos = a.row_ptr[d] + atomicAdd(&a.cursor[d], 1);
        a.colArr[pos] = a.idx32[i];
    }
}

// ---- R19 reg-staged pipeline macros (proven best loop structure) ----------
#define LOADR(tt)                                     \
    do {                                              \
        int k0_ = (tt) << 5;                          \
        rA0 = *(const ushort8v*)(gA0 + k0_);          \
        rA1 = *(const ushort8v*)(gA1 + k0_);          \
        rB0 = *(const ushort8v*)(gB0 + k0_);          \
        rB1 = *(const ushort8v*)(gB1 + k0_);          \
    } while (0)

#define WRITER(b)                                     \
    do {                                              \
        *(ushort8v*)(&As[b][wsl0]) = rA0;             \
        *(ushort8v*)(&As[b][wsl1]) = rA1;             \
        *(ushort8v*)(&Bs[b][wsl0]) = rB0;             \
        *(ushort8v*)(&Bs[b][wsl1]) = rB1;             \
    } while (0)

#define GEMM_PIPELINE(NT)                                                        \
    ushort8v rA0, rA1, rB0, rB1;                                                 \
    LOADR(0);                                                                    \
    WRITER(0);                                                                   \
    LOADR(1);                                                                    \
    asm volatile("s_waitcnt lgkmcnt(0)" ::: "memory");                           \
    __builtin_amdgcn_s_barrier();                                                \
    for (int kt = 0; kt < (NT); ++kt) {                                          \
        int b = kt & 1;                                                          \
        if (kt + 1 < (NT)) WRITER(b ^ 1);                                        \
        if (kt + 2 < (NT)) LOADR(kt + 2);                                        \
        bf16x8 af[4], bfv[4];                                                    \
        _Pragma("unroll")                                                        \
        for (int i = 0; i < 4; i++)                                              \
            af[i] = *(const bf16x8*)(&As[b][(wm + i * 16 + lrow) * 32            \
                                            + lquad * 8]);                       \
        _Pragma("unroll")                                                        \
        for (int j = 0; j < 4; j++)                                              \
            bfv[j] = *(const bf16x8*)(&Bs[b][(wn + j * 16 + lrow) * 32           \
                                             + lquad * 8]);                      \
        _Pragma("unroll")                                                        \
        for (int i = 0; i < 4; i++)                                              \
            _Pragma("unroll")                                                    \
            for (int j = 0; j < 4; j++)                                          \
                acc[i][j] = __builtin_amdgcn_mfma_f32_16x16x32_bf16(             \
                    af[i], bfv[j], acc[i][j], 0, 0, 0);                          \
        asm volatile("s_waitcnt lgkmcnt(0)" ::: "memory");                       \
        __builtin_amdgcn_s_barrier();                                            \
    }

// ---------------- unified GAT GEMM + auxiliary MLP GEMM (front blocks) -----
__global__ __launch_bounds__(256) void gemm_gat(
    const ushort_t* __restrict__ A, const ushort_t* __restrict__ Bt,
    const float* __restrict__ a_src, const float* __restrict__ a_dst,
    ushort_t* __restrict__ Hbf, float* __restrict__ al_s, float* __restrict__ al_d,
    int K, int auxY,
    const ushort_t* __restrict__ xA, const ushort_t* __restrict__ xBt,
    const float* __restrict__ xBias, void* __restrict__ xC,
    int xN, int xK, int xGX, int xCnt, int xAct, float xSlope, int xOutBf) {
    __shared__ __align__(16) ushort_t As[2][128 * 32];
    __shared__ __align__(16) ushort_t Bs[2][128 * 32];
    int t = threadIdx.x;
    int wave = t >> 6, lane = t & 63;
    int wm = (wave >> 1) << 6;
    int wn = (wave & 1) << 6;
    int lrow = lane & 15, lquad = lane >> 4;
    const int wsl0 = (wave * 64 + lane) * 8;
    const int wsl1 = (256 + wave * 64 + lane) * 8;
    int c0 = wave * 64 + lane;
    int c1 = 256 + c0;

    floatx4 acc[4][4];
#pragma unroll
    for (int i = 0; i < 4; i++)
#pragma unroll
        for (int j = 0; j < 4; j++) acc[i][j] = (floatx4){0.f, 0.f, 0.f, 0.f};

    if ((int)blockIdx.y >= auxY) {
        // ---------------- GAT path ----------------
        int rowBase = (blockIdx.y - auxY) << 7;
        int colBase = blockIdx.x << 7;
        const ushort_t* gA0 = A + (size_t)(rowBase + (c0 >> 2)) * K + ((c0 & 3) << 3);
        const ushort_t* gB0 = Bt + (size_t)(colBase + (c0 >> 2)) * K + ((c0 & 3) << 3);
        const ushort_t* gA1 = A + (size_t)(rowBase + (c1 >> 2)) * K + ((c1 & 3) << 3);
        const ushort_t* gB1 = Bt + (size_t)(colBase + (c1 >> 2)) * K + ((c1 & 3) << 3);
        const int nt = K >> 5;   // K in {96,256} -> nt in {3,8}
        GEMM_PIPELINE(nt);

        // epilogue: al_s/al_d per (row, head) + bf16 h store (NCOL=256)
        int head = (colBase + wn) >> 6;
        float avs[4], avd[4];
#pragma unroll
        for (int j = 0; j < 4; j++) {
            avs[j] = a_src[head * 64 + j * 16 + lrow];
            avd[j] = a_dst[head * 64 + j * 16 + lrow];
        }
#pragma unroll
        for (int i = 0; i < 4; i++) {
#pragma unroll
            for (int r = 0; r < 4; r++) {
                float ps = 0.f, pd = 0.f;
#pragma unroll
                for (int j = 0; j < 4; j++) {
                    ps += acc[i][j][r] * avs[j];
                    pd += acc[i][j][r] * avd[j];
                }
#pragma unroll
                for (int off = 1; off < 16; off <<= 1) {
                    ps += __shfl_xor(ps, off);
                    pd += __shfl_xor(pd, off);
                }
                if (lrow == 0) {
                    int gr = rowBase + wm + i * 16 + lquad * 4 + r;
                    al_s[gr * 4 + head] = ps;
                    al_d[gr * 4 + head] = pd;
                }
            }
            int grb = rowBase + wm + i * 16 + lquad * 4;
#pragma unroll
            for (int j = 0; j < 4; j++) {
                int gc = colBase + wn + j * 16 + lrow;
#pragma unroll
                for (int r = 0; r < 4; r++)
                    Hbf[(size_t)(grb + r) * 256 + gc] = f2bf(acc[i][j][r]);
            }
        }
    } else {
        // ---------------- aux MLP GEMM path (front) ----------------
        int id = blockIdx.y * 2 + blockIdx.x;   // gridDim.x == 2
        if (id >= xCnt) return;
        int bxp = id % xGX, byp = id / xGX;
        int rowBase = byp << 7;
        int colBase = bxp << 7;
        const ushort_t* gA0 = xA + (size_t)(rowBase + (c0 >> 2)) * xK + ((c0 & 3) << 3);
        const ushort_t* gB0 = xBt + (size_t)(colBase + (c0 >> 2)) * xK + ((c0 & 3) << 3);
        const ushort_t* gA1 = xA + (size_t)(rowBase + (c1 >> 2)) * xK + ((c1 & 3) << 3);
        const ushort_t* gB1 = xBt + (size_t)(colBase + (c1 >> 2)) * xK + ((c1 & 3) << 3);
        const int nt = xK >> 5;   // K in {64,512} -> nt in {2,16}
        GEMM_PIPELINE(nt);

#pragma unroll
        for (int i = 0; i < 4; i++) {
            int gr = rowBase + wm + i * 16 + lquad * 4;
#pragma unroll
            for (int j = 0; j < 4; j++) {
                int gc = colBase + wn + j * 16 + lrow;
                if (gc >= xN) continue;
                float b = xBias ? xBias[gc] : 0.f;
#pragma unroll
                for (int r = 0; r < 4; r++) {
                    float v = acc[i][j][r] + b;
                    if (xAct) v = lrelu(v, xSlope);
                    if (xOutBf)
                        ((ushort_t*)xC)[(size_t)(gr + r) * xN + gc] = f2bf(v);
                    else
                        ((float*)xC)[(size_t)(gr + r) * xN + gc] = v;
                }
            }
        }
    }
}

// ---------------- bf16 MFMA GEMM (+bias,+lrelu), register-staged (fc) ------
__global__ __launch_bounds__(256) void gemm_plain(
    const ushort_t* __restrict__ A, const ushort_t* __restrict__ Bt,
    const float* __restrict__ bias, void* __restrict__ Cout,
    int M, int N, int K, int act, float slope, int outBf) {
    __shared__ __align__(16) ushort_t As[2][128 * 32];
    __shared__ __align__(16) ushort_t Bs[2][128 * 32];
    int t = threadIdx.x;
    int wave = t >> 6, lane = t & 63;
    int wm = (wave >> 1) << 6;
    int wn = (wave & 1) << 6;
    int rowBase = blockIdx.y << 7;
    int colBase = blockIdx.x << 7;
    int lrow = lane & 15, lquad = lane >> 4;
    floatx4 acc[4][4];
#pragma unroll
    for (int i = 0; i < 4; i++)
#pragma unroll
        for (int j = 0; j < 4; j++) acc[i][j] = (floatx4){0.f, 0.f, 0.f, 0.f};

    int c0 = wave * 64 + lane;
    const ushort_t* gA0 = A + (size_t)(rowBase + (c0 >> 2)) * K + ((c0 & 3) << 3);
    const ushort_t* gB0 = Bt + (size_t)(colBase + (c0 >> 2)) * K + ((c0 & 3) << 3);
    int c1 = 256 + c0;
    const ushort_t* gA1 = A + (size_t)(rowBase + (c1 >> 2)) * K + ((c1 & 3) << 3);
    const ushort_t* gB1 = Bt + (size_t)(colBase + (c1 >> 2)) * K + ((c1 & 3) << 3);
    const int wsl0 = (wave * 64 + lane) * 8;
    const int wsl1 = (256 + wave * 64 + lane) * 8;

    const int nt = K >> 5;   // K = 256 (fc) -> 8
    GEMM_PIPELINE(nt);

#pragma unroll
    for (int i = 0; i < 4; i++) {
        int gr = rowBase + wm + i * 16 + lquad * 4;
#pragma unroll
        for (int j = 0; j < 4; j++) {
            int gc = colBase + wn + j * 16 + lrow;
            if (gc >= N) continue;
            float b = bias ? bias[gc] : 0.f;
#pragma unroll
            for (int r = 0; r < 4; r++) {
                float v = acc[i][j][r] + b;
                if (act) v = lrelu(v, slope);
                if (outBf)
                    ((ushort_t*)Cout)[(size_t)(gr + r) * N + gc] = f2bf(v);
                else
                    ((float*)Cout)[(size_t)(gr + r) * N + gc] = v;
            }
        }
    }
}

// ---------------- aggregation: TWO nodes per wave, batch-4 gather ------------
// lanes 0-31 -> node A, 32-63 -> node B; 16B/lane (8 channels, ushort8).
__global__ __launch_bounds__(256) void gat_agg(
    const ushort_t* __restrict__ h_bf, const float* __restrict__ al_s,
    const float* __restrict__ al_d, const int* __restrict__ row_ptr,
    const int* __restrict__ col, const float* __restrict__ bias,
    ushort_t* __restrict__ out_bf, int N, int act, float slope) {
    int wid = (blockIdx.x * 256 + threadIdx.x) >> 6;   // wave index
    int lane = threadIdx.x & 63;
    int half = lane >> 5;
    int lane8 = lane & 31;
    int n = wid * 2 + half;
    if (n >= N) return;
    int head = lane8 >> 3;                 // 8 lanes per head, 8 ch per lane
    int idx4 = n * 4 + head;
    float ad = al_d[idx4];
    const ushort8v* h8 = (const ushort8v*)h_bf;   // row stride 32 ushort8
    // self loop
    float p = __expf(lrelu(al_s[idx4] + ad, GAT_SLOPE));
    ushort8v hv = h8[(size_t)n * 32 + lane8];
    float s = p;
    float acc[8];
#pragma unroll
    for (int c = 0; c < 8; c++) acc[c] = p * bf2f(hv[c]);
    int beg = row_ptr[n], end = row_ptr[n + 1];
    for (int i = beg; i < end; i += 4) {
        int cnt = end - i;
        int sn0 = col[i];
        int sn1 = (cnt > 1) ? col[i + 1] : sn0;
        int sn2 = (cnt > 2) ? col[i + 2] : sn0;
        int sn3 = (cnt > 3) ? col[i + 3] : sn0;
        ushort8v h0 = h8[(size_t)sn0 * 32 + lane8];
        ushort8v h1 = h8[(size_t)sn1 * 32 + lane8];
        ushort8v h2 = h8[(size_t)sn2 * 32 + lane8];
        ushort8v h3 = h8[(size_t)sn3 * 32 + lane8];
        float a0 = al_s[sn0 * 4 + head];
        float a1 = al_s[sn1 * 4 + head];
        float a2 = al_s[sn2 * 4 + head];
        float a3 = al_s[sn3 * 4 + head];
        float p0 = __expf(lrelu(a0 + ad, GAT_SLOPE));
#pragma unroll
        for (int c = 0; c < 8; c++) acc[c] += p0 * bf2f(h0[c]);
        s += p0;
        if (cnt > 1) {
            float p1 = __expf(lrelu(a1 + ad, GAT_SLOPE));
#pragma unroll
            for (int c = 0; c < 8; c++) acc[c] += p1 * bf2f(h1[c]);
            s += p1;
        }
        if (cnt > 2) {
            float p2 = __expf(lrelu(a2 + ad, GAT_SLOPE));
#pragma unroll
            for (int c = 0; c < 8; c++) acc[c] += p2 * bf2f(h2[c]);
            s += p2;
        }
        if (cnt > 3) {
            float p3 = __expf(lrelu(a3 + ad, GAT_SLOPE));
#pragma unroll
            for (int c = 0; c < 8; c++) acc[c] += p3 * bf2f(h3[c]);
            s += p3;
        }
    }
    float rs = 1.f / s;
    const float4* b4 = (const float4*)bias;
    float4 b0 = b4[lane8 * 2];
    float4 b1 = b4[lane8 * 2 + 1];
    float bv[8] = {b0.x, b0.y, b0.z, b0.w, b1.x, b1.y, b1.z, b1.w};
    ushort8v o;
#pragma unroll
    for (int c = 0; c < 8; c++) {
        float v = acc[c] * rs + bv[c];
        if (act) v = lrelu(v, slope);
        o[c] = f2bf(v);
    }
    ((ushort8v*)out_bf)[(size_t)n * 32 + lane8] = o;
}

// ---------------------------------------------------------------------------
extern "C" void kernel_launch(void* const* d_in, const int* in_sizes, int n_in,
                              void* d_out, int out_size, void* d_ws, size_t ws_size,
                              hipStream_t stream) {
    const float* x        = (const float*)d_in[0];
    const int*   rawEdge  = (const int*)d_in[1];
    const float* rootCtx  = (const float*)d_in[2];
    const float* W[3]     = {(const float*)d_in[3], (const float*)d_in[7], (const float*)d_in[11]};
    const float* aS[3]    = {(const float*)d_in[4], (const float*)d_in[8], (const float*)d_in[12]};
    const float* aD[3]    = {(const float*)d_in[5], (const float*)d_in[9], (const float*)d_in[13]};
    const float* bb[3]    = {(const float*)d_in[6], (const float*)d_in[10], (const float*)d_in[14]};
    const float* fc_w     = (const float*)d_in[15];
    const float* fc_b     = (const float*)d_in[16];
    const float* r_w1     = (const float*)d_in[17];
    const float* r_b1     = (const float*)d_in[18];
    const float* r_w2     = (const float*)d_in[19];
    const float* r_b2     = (const float*)d_in[20];
    const float* r_w3     = (const float*)d_in[21];
    const float* r_b3     = (const float*)d_in[22];

    const int N  = in_sizes[0] / 80;      // 102400
    const int E  = in_sizes[1] / 2;       // 409600
    const int R  = in_sizes[2] / 60;      // 4096
    const int N4 = N * 4;

    float* outRot  = (float*)d_out;                  // [N, 80]
    float* outRoot = (float*)d_out + (size_t)N * 80; // [R, 60]

    // ---- carve workspace ----
    size_t off = 0;
    auto carve = [&](size_t bytes) -> void* {
        off = (off + 255) & ~(size_t)255;
        void* p = (char*)d_ws + off;
        off += bytes;
        return p;
    };
    int*      flag      = (int*)carve(4);
    int*      idx32     = (int*)carve((size_t)2 * E * 4);
    int*      counts    = (int*)carve((size_t)N * 4);
    int*      cursor    = (int*)carve((size_t)N * 4);
    int*      row_ptr   = (int*)carve((size_t)(N + 1) * 4);
    int*      incArr    = (int*)carve((size_t)N * 4);
    int*      blockSums = (int*)carve(512 * 4);
    int*      colArr    = (int*)carve((size_t)E * 4);
    float*    al_s      = (float*)carve((size_t)N4 * 4);
    float*    al_d      = (float*)carve((size_t)N4 * 4);
    ushort_t* h_bf      = (ushort_t*)carve((size_t)N * 256 * 2);
    ushort_t* agg_bf    = (ushort_t*)carve((size_t)N * 256 * 2);
    ushort_t* x_bf      = (ushort_t*)carve((size_t)N * 96 * 2);    // Kp=96
    ushort_t* rc_bf     = (ushort_t*)carve((size_t)R * 64 * 2);
    ushort_t* t1_bf     = (ushort_t*)carve((size_t)R * 512 * 2);
    ushort_t* t2_bf     = (ushort_t*)carve((size_t)R * 512 * 2);
    ushort_t* Wt0       = (ushort_t*)carve((size_t)256 * 96 * 2);  // Kp=96
    ushort_t* Wt1       = (ushort_t*)carve((size_t)256 * 256 * 2);
    ushort_t* Wt2       = (ushort_t*)carve((size_t)256 * 256 * 2);
    ushort_t* fcWt      = (ushort_t*)carve((size_t)128 * 256 * 2);
    ushort_t* rW1t      = (ushort_t*)carve((size_t)512 * 64 * 2);
    ushort_t* rWt2      = (ushort_t*)carve((size_t)512 * 512 * 2);
    ushort_t* rWt3     = (ushort_t*)carve((size_t)128 * 512 * 2);

    dim3 blk(256);

    // ---- single cooperative preamble: CSR + all conversions ----
    {
        PreArgs pa;
        pa.rawEdge = rawEdge; pa.E = E; pa.N = N; pa.R = R;
        pa.flag = flag; pa.idx32 = idx32; pa.counts = counts; pa.cursor = cursor;
        pa.row_ptr = row_ptr; pa.incArr = incArr; pa.blockSums = blockSums;
        pa.colArr = colArr;
        pa.x = x; pa.x_bf = x_bf; pa.rc = rootCtx; pa.rc_bf = rc_bf;
        pa.w[0] = WConv{W[0], Wt0, 96, 80, 256, 256};
        pa.w[1] = WConv{W[1], Wt1, 256, 256, 256, 256};
        pa.w[2] = WConv{W[2], Wt2, 256, 256, 256, 256};
        pa.w[3] = WConv{fc_w, fcWt, 256, 256, 80, 128};
        pa.w[4] = WConv{r_w1, rW1t, 64, 60, 512, 512};
        pa.w[5] = WConv{r_w2, rWt2, 512, 512, 512, 512};
        pa.w[6] = WConv{r_w3, rWt3, 512, 512, 60, 128};
        void* kargs[] = { (void*)&pa };
        hipLaunchCooperativeKernel((void*)preamble_all, dim3(1024), blk,
                                   kargs, 0, stream);
    }

    // ---- GAT layers with fused MLP-chain aux blocks (front-placed) ----
    const int aggBlocks = (N / 2 + 3) / 4;   // 2 nodes/wave, 4 waves/block
    const int yMain = N / 128;               // 800
    const ushort_t* curA = x_bf;
    int curK = 96;
    const int mlpGY = R / 128;               // 32
    for (int l = 0; l < 3; l++) {
        // aux GEMM for this launch: MLP layer l
        const ushort_t* xA  = (l == 0) ? rc_bf : (l == 1 ? t1_bf : t2_bf);
        const ushort_t* xBt = (l == 0) ? rW1t : (l == 1 ? rWt2 : rWt3);
        const float*    xB  = (l == 0) ? r_b1 : (l == 1 ? r_b2 : r_b3);
        void*           xC  = (l == 0) ? (void*)t1_bf : (l == 1 ? (void*)t2_bf : (void*)outRoot);
        int xN   = (l == 2) ? 60 : 512;
        int xK   = (l == 0) ? 64 : 512;
        int xGX  = (l == 2) ? 1 : 4;
        int xCnt = xGX * mlpGY;              // 128,128,32
        int xAct = (l == 2) ? 0 : 1;
        int xOutBf = (l == 2) ? 0 : 1;
        int auxY = (xCnt + 1) / 2;           // gridDim.x = 2
        dim3 g1(2, yMain + auxY);
        gemm_gat<<<g1, blk, 0, stream>>>(curA, l == 0 ? Wt0 : (l == 1 ? Wt1 : Wt2),
                                         aS[l], aD[l], h_bf, al_s, al_d,
                                         curK, auxY,
                                         xA, xBt, xB, xC,
                                         xN, xK, xGX, xCnt, xAct, ACT_SLOPE, xOutBf);
        int act = (l < 2) ? 1 : 0;
        gat_agg<<<aggBlocks, blk, 0, stream>>>(h_bf, al_s, al_d, row_ptr,
                                               colArr, bb[l], agg_bf, N,
                                               act, ACT_SLOPE);
        curA = agg_bf;
        curK = 256;
    }

    // ---- rot = h @ fc_w + fc_b ----
    {
        dim3 g(1, N / 128);
        gemm_plain<<<g, blk, 0, stream>>>(agg_bf, fcWt, fc_b, outRot, N, 80, 256,
                                          0, 0.f, 0);
    }
}

// Round 16
// 459.175 us; speedup vs baseline: 2.2604x; 2.2604x over previous
//
#include <hip/hip_runtime.h>
#include <hip/hip_bf16.h>

// ---------------------------------------------------------------------------
// GAT x3 + fc + MLP. R26 = R24 (best, 469.4us) with the preamble compressed
// WITHOUT cooperative sync (R25's grid.sync cost ~120us each -> 1038us total;
// reverted). 10 preamble dispatches -> 6:
//   hipMemsetAsync(counts+cursor)  [contiguous, 256-aligned]
//   init_all: detect_fmt (per-block recompute) + edge convert/count +
//             x/rc pad-convert + 7 weight transposes (all independent)
//   scan_block / scan_sums / scan_add / edge_fill (dependency chain, kept)
// Hot kernels byte-identical to R24: gemm_gat with front-placed aux MLP
// blocks, gat_agg at measured gather-fabric roofline, reg-staged fc.
// ---------------------------------------------------------------------------

#define GAT_SLOPE 0.2f
#define ACT_SLOPE 0.01f

typedef unsigned short ushort_t;
typedef __attribute__((ext_vector_type(8))) short bf16x8;
typedef __attribute__((ext_vector_type(8))) unsigned short ushort8v;
typedef __attribute__((ext_vector_type(4))) float floatx4;

__device__ __forceinline__ float lrelu(float x, float s) {
    return fmaxf(x, s * x);   // valid for 0<s<1
}

__device__ __forceinline__ ushort_t f2bf(float f) {
    union { float f; unsigned u; } x; x.f = f;
    unsigned r = x.u + 0x7FFF + ((x.u >> 16) & 1);   // round-nearest-even
    return (ushort_t)(r >> 16);
}

__device__ __forceinline__ float bf2f(ushort_t u) {
    union { unsigned u; float f; } x; x.u = ((unsigned)u) << 16;
    return x.f;
}

// ---------------- fused init: flag + edge count + all conversions ----------
struct WConv { const float* in; ushort_t* out; int Kp, Kr, N, Npad; };

struct InitArgs {
    const int* rawEdge;
    int E, N, R;
    int* idx32;      // [2E]
    int* counts;     // pre-zeroed by memset
    const float* x;  ushort_t* x_bf;    // N x 96 (pad from 80)
    const float* rc; ushort_t* rc_bf;   // R x 64 (pad from 60)
    WConv w[7];
};

__global__ __launch_bounds__(256) void init_all(InitArgs a) {
    const int tid  = blockIdx.x * blockDim.x + threadIdx.x;
    const int nthr = gridDim.x * blockDim.x;

    // per-block edge-format recompute (first 4KB, L2-hot, ~free)
    __shared__ int nzs;
    if (threadIdx.x == 0) nzs = 0;
    __syncthreads();
    int lim = 2 * a.E < 4096 ? 2 * a.E : 4096;
    for (int i = threadIdx.x * 2 + 1; i < lim; i += 512)
        if (a.rawEdge[i] != 0) atomicAdd(&nzs, 1);
    __syncthreads();
    const int fmt = (nzs == 0) ? 1 : 0;   // 1 => int64 storage

    // edge convert + degree count (counts pre-zeroed)
    for (int i = tid; i < a.E; i += nthr) {
        int s = fmt ? a.rawEdge[2 * i] : a.rawEdge[i];
        int d = fmt ? a.rawEdge[2 * (a.E + i)] : a.rawEdge[a.E + i];
        a.idx32[i] = s;
        a.idx32[a.E + i] = d;
        atomicAdd(&a.counts[d], 1);
    }
    // x pad-convert (80 -> 96)
    {
        int tot = a.N * 96;
        for (int i = tid; i < tot; i += nthr) {
            int r = i / 96, c = i - r * 96;
            a.x_bf[i] = f2bf((c < 80) ? a.x[(size_t)r * 80 + c] : 0.f);
        }
    }
    // rc pad-convert (60 -> 64)
    {
        int tot = a.R * 64;
        for (int i = tid; i < tot; i += nthr) {
            int r = i >> 6, c = i & 63;
            a.rc_bf[i] = f2bf((c < 60) ? a.rc[(size_t)r * 60 + c] : 0.f);
        }
    }
    // 7 weight transposes
    for (int e = 0; e < 7; e++) {
        WConv w = a.w[e];
        int tot = w.Npad * w.Kp;
        for (int i = tid; i < tot; i += nthr) {
            int n = i / w.Kp, k = i - n * w.Kp;
            float v = (n < w.N && k < w.Kr) ? w.in[(size_t)k * w.N + n] : 0.f;
            w.out[i] = f2bf(v);
        }
    }
}

__global__ void scan_block(const int* __restrict__ counts, int* __restrict__ inc,
                           int* __restrict__ blockSums, int N) {
    __shared__ int sh[256];
    int i = blockIdx.x * 256 + threadIdx.x;
    int v = (i < N) ? counts[i] : 0;
    sh[threadIdx.x] = v;
    __syncthreads();
    for (int off = 1; off < 256; off <<= 1) {
        int t = (threadIdx.x >= off) ? sh[threadIdx.x - off] : 0;
        __syncthreads();
        sh[threadIdx.x] += t;
        __syncthreads();
    }
    if (i < N) inc[i] = sh[threadIdx.x];
    if (threadIdx.x == 255) blockSums[blockIdx.x] = sh[255];
}

__global__ void scan_sums(int* __restrict__ blockSums, int nb, int* __restrict__ row_ptr) {
    __shared__ int sh[512];
    int v = ((int)threadIdx.x < nb) ? blockSums[threadIdx.x] : 0;
    sh[threadIdx.x] = v;
    __syncthreads();
    for (int off = 1; off < 512; off <<= 1) {
        int t = (threadIdx.x >= off) ? sh[threadIdx.x - off] : 0;
        __syncthreads();
        sh[threadIdx.x] += t;
        __syncthreads();
    }
    if ((int)threadIdx.x < nb) blockSums[threadIdx.x] = sh[threadIdx.x];
    if (threadIdx.x == 0) row_ptr[0] = 0;
}

__global__ void scan_add(const int* __restrict__ inc, const int* __restrict__ blockSums,
                         int* __restrict__ row_ptr, int N) {
    int i = blockIdx.x * 256 + threadIdx.x;
    if (i < N) row_ptr[i + 1] = inc[i] + (blockIdx.x > 0 ? blockSums[blockIdx.x - 1] : 0);
}

__global__ void edge_fill(const int* __restrict__ src, const int* __restrict__ dst, int E,
                          const int* __restrict__ row_ptr, int* __restrict__ cursor,
                          int* __restrict__ col) {
    int i = blockIdx.x * blockDim.x + threadIdx.x;
    if (i < E) {
        int d = dst[i];
        int pos = row_ptr[d] + atomicAdd(&cursor[d], 1);
        col[pos] = src[i];
    }
}

// ---- R19 reg-staged pipeline macros (proven best loop structure) ----------
#define LOADR(tt)                                     \
    do {                                              \
        int k0_ = (tt) << 5;                          \
        rA0 = *(const ushort8v*)(gA0 + k0_);          \
        rA1 = *(const ushort8v*)(gA1 + k0_);          \
        rB0 = *(const ushort8v*)(gB0 + k0_);          \
        rB1 = *(const ushort8v*)(gB1 + k0_);          \
    } while (0)

#define WRITER(b)                                     \
    do {                                              \
        *(ushort8v*)(&As[b][wsl0]) = rA0;             \
        *(ushort8v*)(&As[b][wsl1]) = rA1;             \
        *(ushort8v*)(&Bs[b][wsl0]) = rB0;             \
        *(ushort8v*)(&Bs[b][wsl1]) = rB1;             \
    } while (0)

#define GEMM_PIPELINE(NT)                                                        \
    ushort8v rA0, rA1, rB0, rB1;                                                 \
    LOADR(0);                                                                    \
    WRITER(0);                                                                   \
    LOADR(1);                                                                    \
    asm volatile("s_waitcnt lgkmcnt(0)" ::: "memory");                           \
    __builtin_amdgcn_s_barrier();                                                \
    for (int kt = 0; kt < (NT); ++kt) {                                          \
        int b = kt & 1;                                                          \
        if (kt + 1 < (NT)) WRITER(b ^ 1);                                        \
        if (kt + 2 < (NT)) LOADR(kt + 2);                                        \
        bf16x8 af[4], bfv[4];                                                    \
        _Pragma("unroll")                                                        \
        for (int i = 0; i < 4; i++)                                              \
            af[i] = *(const bf16x8*)(&As[b][(wm + i * 16 + lrow) * 32            \
                                            + lquad * 8]);                       \
        _Pragma("unroll")                                                        \
        for (int j = 0; j < 4; j++)                                              \
            bfv[j] = *(const bf16x8*)(&Bs[b][(wn + j * 16 + lrow) * 32           \
                                             + lquad * 8]);                      \
        _Pragma("unroll")                                                        \
        for (int i = 0; i < 4; i++)                                              \
            _Pragma("unroll")                                                    \
            for (int j = 0; j < 4; j++)                                          \
                acc[i][j] = __builtin_amdgcn_mfma_f32_16x16x32_bf16(             \
                    af[i], bfv[j], acc[i][j], 0, 0, 0);                          \
        asm volatile("s_waitcnt lgkmcnt(0)" ::: "memory");                       \
        __builtin_amdgcn_s_barrier();                                            \
    }

// ---------------- unified GAT GEMM + auxiliary MLP GEMM (front blocks) -----
__global__ __launch_bounds__(256) void gemm_gat(
    const ushort_t* __restrict__ A, const ushort_t* __restrict__ Bt,
    const float* __restrict__ a_src, const float* __restrict__ a_dst,
    ushort_t* __restrict__ Hbf, float* __restrict__ al_s, float* __restrict__ al_d,
    int K, int auxY,
    const ushort_t* __restrict__ xA, const ushort_t* __restrict__ xBt,
    const float* __restrict__ xBias, void* __restrict__ xC,
    int xN, int xK, int xGX, int xCnt, int xAct, float xSlope, int xOutBf) {
    __shared__ __align__(16) ushort_t As[2][128 * 32];
    __shared__ __align__(16) ushort_t Bs[2][128 * 32];
    int t = threadIdx.x;
    int wave = t >> 6, lane = t & 63;
    int wm = (wave >> 1) << 6;
    int wn = (wave & 1) << 6;
    int lrow = lane & 15, lquad = lane >> 4;
    const int wsl0 = (wave * 64 + lane) * 8;
    const int wsl1 = (256 + wave * 64 + lane) * 8;
    int c0 = wave * 64 + lane;
    int c1 = 256 + c0;

    floatx4 acc[4][4];
#pragma unroll
    for (int i = 0; i < 4; i++)
#pragma unroll
        for (int j = 0; j < 4; j++) acc[i][j] = (floatx4){0.f, 0.f, 0.f, 0.f};

    if ((int)blockIdx.y >= auxY) {
        // ---------------- GAT path ----------------
        int rowBase = (blockIdx.y - auxY) << 7;
        int colBase = blockIdx.x << 7;
        const ushort_t* gA0 = A + (size_t)(rowBase + (c0 >> 2)) * K + ((c0 & 3) << 3);
        const ushort_t* gB0 = Bt + (size_t)(colBase + (c0 >> 2)) * K + ((c0 & 3) << 3);
        const ushort_t* gA1 = A + (size_t)(rowBase + (c1 >> 2)) * K + ((c1 & 3) << 3);
        const ushort_t* gB1 = Bt + (size_t)(colBase + (c1 >> 2)) * K + ((c1 & 3) << 3);
        const int nt = K >> 5;   // K in {96,256} -> nt in {3,8}
        GEMM_PIPELINE(nt);

        // epilogue: al_s/al_d per (row, head) + bf16 h store (NCOL=256)
        int head = (colBase + wn) >> 6;
        float avs[4], avd[4];
#pragma unroll
        for (int j = 0; j < 4; j++) {
            avs[j] = a_src[head * 64 + j * 16 + lrow];
            avd[j] = a_dst[head * 64 + j * 16 + lrow];
        }
#pragma unroll
        for (int i = 0; i < 4; i++) {
#pragma unroll
            for (int r = 0; r < 4; r++) {
                float ps = 0.f, pd = 0.f;
#pragma unroll
                for (int j = 0; j < 4; j++) {
                    ps += acc[i][j][r] * avs[j];
                    pd += acc[i][j][r] * avd[j];
                }
#pragma unroll
                for (int off = 1; off < 16; off <<= 1) {
                    ps += __shfl_xor(ps, off);
                    pd += __shfl_xor(pd, off);
                }
                if (lrow == 0) {
                    int gr = rowBase + wm + i * 16 + lquad * 4 + r;
                    al_s[gr * 4 + head] = ps;
                    al_d[gr * 4 + head] = pd;
                }
            }
            int grb = rowBase + wm + i * 16 + lquad * 4;
#pragma unroll
            for (int j = 0; j < 4; j++) {
                int gc = colBase + wn + j * 16 + lrow;
#pragma unroll
                for (int r = 0; r < 4; r++)
                    Hbf[(size_t)(grb + r) * 256 + gc] = f2bf(acc[i][j][r]);
            }
        }
    } else {
        // ---------------- aux MLP GEMM path (front) ----------------
        int id = blockIdx.y * 2 + blockIdx.x;   // gridDim.x == 2
        if (id >= xCnt) return;
        int bxp = id % xGX, byp = id / xGX;
        int rowBase = byp << 7;
        int colBase = bxp << 7;
        const ushort_t* gA0 = xA + (size_t)(rowBase + (c0 >> 2)) * xK + ((c0 & 3) << 3);
        const ushort_t* gB0 = xBt + (size_t)(colBase + (c0 >> 2)) * xK + ((c0 & 3) << 3);
        const ushort_t* gA1 = xA + (size_t)(rowBase + (c1 >> 2)) * xK + ((c1 & 3) << 3);
        const ushort_t* gB1 = xBt + (size_t)(colBase + (c1 >> 2)) * xK + ((c1 & 3) << 3);
        const int nt = xK >> 5;   // K in {64,512} -> nt in {2,16}
        GEMM_PIPELINE(nt);

#pragma unroll
        for (int i = 0; i < 4; i++) {
            int gr = rowBase + wm + i * 16 + lquad * 4;
#pragma unroll
            for (int j = 0; j < 4; j++) {
                int gc = colBase + wn + j * 16 + lrow;
                if (gc >= xN) continue;
                float b = xBias ? xBias[gc] : 0.f;
#pragma unroll
                for (int r = 0; r < 4; r++) {
                    float v = acc[i][j][r] + b;
                    if (xAct) v = lrelu(v, xSlope);
                    if (xOutBf)
                        ((ushort_t*)xC)[(size_t)(gr + r) * xN + gc] = f2bf(v);
                    else
                        ((float*)xC)[(size_t)(gr + r) * xN + gc] = v;
                }
            }
        }
    }
}

// ---------------- bf16 MFMA GEMM (+bias,+lrelu), register-staged (fc) ------
__global__ __launch_bounds__(256) void gemm_plain(
    const ushort_t* __restrict__ A, const ushort_t* __restrict__ Bt,
    const float* __restrict__ bias, void* __restrict__ Cout,
    int M, int N, int K, int act, float slope, int outBf) {
    __shared__ __align__(16) ushort_t As[2][128 * 32];
    __shared__ __align__(16) ushort_t Bs[2][128 * 32];
    int t = threadIdx.x;
    int wave = t >> 6, lane = t & 63;
    int wm = (wave >> 1) << 6;
    int wn = (wave & 1) << 6;
    int rowBase = blockIdx.y << 7;
    int colBase = blockIdx.x << 7;
    int lrow = lane & 15, lquad = lane >> 4;
    floatx4 acc[4][4];
#pragma unroll
    for (int i = 0; i < 4; i++)
#pragma unroll
        for (int j = 0; j < 4; j++) acc[i][j] = (floatx4){0.f, 0.f, 0.f, 0.f};

    int c0 = wave * 64 + lane;
    const ushort_t* gA0 = A + (size_t)(rowBase + (c0 >> 2)) * K + ((c0 & 3) << 3);
    const ushort_t* gB0 = Bt + (size_t)(colBase + (c0 >> 2)) * K + ((c0 & 3) << 3);
    int c1 = 256 + c0;
    const ushort_t* gA1 = A + (size_t)(rowBase + (c1 >> 2)) * K + ((c1 & 3) << 3);
    const ushort_t* gB1 = Bt + (size_t)(colBase + (c1 >> 2)) * K + ((c1 & 3) << 3);
    const int wsl0 = (wave * 64 + lane) * 8;
    const int wsl1 = (256 + wave * 64 + lane) * 8;

    const int nt = K >> 5;   // K = 256 (fc) -> 8
    GEMM_PIPELINE(nt);

#pragma unroll
    for (int i = 0; i < 4; i++) {
        int gr = rowBase + wm + i * 16 + lquad * 4;
#pragma unroll
        for (int j = 0; j < 4; j++) {
            int gc = colBase + wn + j * 16 + lrow;
            if (gc >= N) continue;
            float b = bias ? bias[gc] : 0.f;
#pragma unroll
            for (int r = 0; r < 4; r++) {
                float v = acc[i][j][r] + b;
                if (act) v = lrelu(v, slope);
                if (outBf)
                    ((ushort_t*)Cout)[(size_t)(gr + r) * N + gc] = f2bf(v);
                else
                    ((float*)Cout)[(size_t)(gr + r) * N + gc] = v;
            }
        }
    }
}

// ---------------- aggregation: TWO nodes per wave, batch-4 gather ------------
// lanes 0-31 -> node A, 32-63 -> node B; 16B/lane (8 channels, ushort8).
__global__ __launch_bounds__(256) void gat_agg(
    const ushort_t* __restrict__ h_bf, const float* __restrict__ al_s,
    const float* __restrict__ al_d, const int* __restrict__ row_ptr,
    const int* __restrict__ col, const float* __restrict__ bias,
    ushort_t* __restrict__ out_bf, int N, int act, float slope) {
    int wid = (blockIdx.x * 256 + threadIdx.x) >> 6;   // wave index
    int lane = threadIdx.x & 63;
    int half = lane >> 5;
    int lane8 = lane & 31;
    int n = wid * 2 + half;
    if (n >= N) return;
    int head = lane8 >> 3;                 // 8 lanes per head, 8 ch per lane
    int idx4 = n * 4 + head;
    float ad = al_d[idx4];
    const ushort8v* h8 = (const ushort8v*)h_bf;   // row stride 32 ushort8
    // self loop
    float p = __expf(lrelu(al_s[idx4] + ad, GAT_SLOPE));
    ushort8v hv = h8[(size_t)n * 32 + lane8];
    float s = p;
    float acc[8];
#pragma unroll
    for (int c = 0; c < 8; c++) acc[c] = p * bf2f(hv[c]);
    int beg = row_ptr[n], end = row_ptr[n + 1];
    for (int i = beg; i < end; i += 4) {
        int cnt = end - i;
        int sn0 = col[i];
        int sn1 = (cnt > 1) ? col[i + 1] : sn0;
        int sn2 = (cnt > 2) ? col[i + 2] : sn0;
        int sn3 = (cnt > 3) ? col[i + 3] : sn0;
        ushort8v h0 = h8[(size_t)sn0 * 32 + lane8];
        ushort8v h1 = h8[(size_t)sn1 * 32 + lane8];
        ushort8v h2 = h8[(size_t)sn2 * 32 + lane8];
        ushort8v h3 = h8[(size_t)sn3 * 32 + lane8];
        float a0 = al_s[sn0 * 4 + head];
        float a1 = al_s[sn1 * 4 + head];
        float a2 = al_s[sn2 * 4 + head];
        float a3 = al_s[sn3 * 4 + head];
        float p0 = __expf(lrelu(a0 + ad, GAT_SLOPE));
#pragma unroll
        for (int c = 0; c < 8; c++) acc[c] += p0 * bf2f(h0[c]);
        s += p0;
        if (cnt > 1) {
            float p1 = __expf(lrelu(a1 + ad, GAT_SLOPE));
#pragma unroll
            for (int c = 0; c < 8; c++) acc[c] += p1 * bf2f(h1[c]);
            s += p1;
        }
        if (cnt > 2) {
            float p2 = __expf(lrelu(a2 + ad, GAT_SLOPE));
#pragma unroll
            for (int c = 0; c < 8; c++) acc[c] += p2 * bf2f(h2[c]);
            s += p2;
        }
        if (cnt > 3) {
            float p3 = __expf(lrelu(a3 + ad, GAT_SLOPE));
#pragma unroll
            for (int c = 0; c < 8; c++) acc[c] += p3 * bf2f(h3[c]);
            s += p3;
        }
    }
    float rs = 1.f / s;
    const float4* b4 = (const float4*)bias;
    float4 b0 = b4[lane8 * 2];
    float4 b1 = b4[lane8 * 2 + 1];
    float bv[8] = {b0.x, b0.y, b0.z, b0.w, b1.x, b1.y, b1.z, b1.w};
    ushort8v o;
#pragma unroll
    for (int c = 0; c < 8; c++) {
        float v = acc[c] * rs + bv[c];
        if (act) v = lrelu(v, slope);
        o[c] = f2bf(v);
    }
    ((ushort8v*)out_bf)[(size_t)n * 32 + lane8] = o;
}

// ---------------------------------------------------------------------------
extern "C" void kernel_launch(void* const* d_in, const int* in_sizes, int n_in,
                              void* d_out, int out_size, void* d_ws, size_t ws_size,
                              hipStream_t stream) {
    const float* x        = (const float*)d_in[0];
    const int*   rawEdge  = (const int*)d_in[1];
    const float* rootCtx  = (const float*)d_in[2];
    const float* W[3]     = {(const float*)d_in[3], (const float*)d_in[7], (const float*)d_in[11]};
    const float* aS[3]    = {(const float*)d_in[4], (const float*)d_in[8], (const float*)d_in[12]};
    const float* aD[3]    = {(const float*)d_in[5], (const float*)d_in[9], (const float*)d_in[13]};
    const float* bb[3]    = {(const float*)d_in[6], (const float*)d_in[10], (const float*)d_in[14]};
    const float* fc_w     = (const float*)d_in[15];
    const float* fc_b     = (const float*)d_in[16];
    const float* r_w1     = (const float*)d_in[17];
    const float* r_b1     = (const float*)d_in[18];
    const float* r_w2     = (const float*)d_in[19];
    const float* r_b2     = (const float*)d_in[20];
    const float* r_w3     = (const float*)d_in[21];
    const float* r_b3     = (const float*)d_in[22];

    const int N  = in_sizes[0] / 80;      // 102400
    const int E  = in_sizes[1] / 2;       // 409600
    const int R  = in_sizes[2] / 60;      // 4096
    const int N4 = N * 4;

    float* outRot  = (float*)d_out;                  // [N, 80]
    float* outRoot = (float*)d_out + (size_t)N * 80; // [R, 60]

    // ---- carve workspace ----
    size_t off = 0;
    auto carve = [&](size_t bytes) -> void* {
        off = (off + 255) & ~(size_t)255;
        void* p = (char*)d_ws + off;
        off += bytes;
        return p;
    };
    int*      flag      = (int*)carve(4);
    int*      idx32     = (int*)carve((size_t)2 * E * 4);
    int*      counts    = (int*)carve((size_t)N * 4);
    int*      cursor    = (int*)carve((size_t)N * 4);
    int*      row_ptr   = (int*)carve((size_t)(N + 1) * 4);
    int*      incArr    = (int*)carve((size_t)N * 4);
    int*      blockSums = (int*)carve(512 * 4);
    int*      colArr    = (int*)carve((size_t)E * 4);
    float*    al_s      = (float*)carve((size_t)N4 * 4);
    float*    al_d      = (float*)carve((size_t)N4 * 4);
    ushort_t* h_bf      = (ushort_t*)carve((size_t)N * 256 * 2);
    ushort_t* agg_bf    = (ushort_t*)carve((size_t)N * 256 * 2);
    ushort_t* x_bf      = (ushort_t*)carve((size_t)N * 96 * 2);    // Kp=96
    ushort_t* rc_bf     = (ushort_t*)carve((size_t)R * 64 * 2);
    ushort_t* t1_bf     = (ushort_t*)carve((size_t)R * 512 * 2);
    ushort_t* t2_bf     = (ushort_t*)carve((size_t)R * 512 * 2);
    ushort_t* Wt0       = (ushort_t*)carve((size_t)256 * 96 * 2);  // Kp=96
    ushort_t* Wt1       = (ushort_t*)carve((size_t)256 * 256 * 2);
    ushort_t* Wt2       = (ushort_t*)carve((size_t)256 * 256 * 2);
    ushort_t* fcWt      = (ushort_t*)carve((size_t)128 * 256 * 2);
    ushort_t* rW1t      = (ushort_t*)carve((size_t)512 * 64 * 2);
    ushort_t* rWt2      = (ushort_t*)carve((size_t)512 * 512 * 2);
    ushort_t* rWt3      = (ushort_t*)carve((size_t)128 * 512 * 2);

    const int nb = (N + 255) / 256;
    dim3 blk(256);

    // ---- compressed preamble ----
    // counts and cursor are contiguous (N*4 = 409600 bytes, 256-aligned)
    hipMemsetAsync(counts, 0, (size_t)2 * N * 4, stream);
    {
        InitArgs ia;
        ia.rawEdge = rawEdge; ia.E = E; ia.N = N; ia.R = R;
        ia.idx32 = idx32; ia.counts = counts;
        ia.x = x; ia.x_bf = x_bf; ia.rc = rootCtx; ia.rc_bf = rc_bf;
        ia.w[0] = WConv{W[0], Wt0, 96, 80, 256, 256};
        ia.w[1] = WConv{W[1], Wt1, 256, 256, 256, 256};
        ia.w[2] = WConv{W[2], Wt2, 256, 256, 256, 256};
        ia.w[3] = WConv{fc_w, fcWt, 256, 256, 80, 128};
        ia.w[4] = WConv{r_w1, rW1t, 64, 60, 512, 512};
        ia.w[5] = WConv{r_w2, rWt2, 512, 512, 512, 512};
        ia.w[6] = WConv{r_w3, rWt3, 512, 512, 60, 128};
        init_all<<<2048, blk, 0, stream>>>(ia);
    }
    const int* srcArr = idx32;
    const int* dstArr = idx32 + E;
    scan_block<<<nb, 256, 0, stream>>>(counts, incArr, blockSums, N);
    scan_sums<<<1, 512, 0, stream>>>(blockSums, nb, row_ptr);
    scan_add<<<nb, 256, 0, stream>>>(incArr, blockSums, row_ptr, N);
    edge_fill<<<(E + 255) / 256, blk, 0, stream>>>(srcArr, dstArr, E, row_ptr, cursor, colArr);
    (void)flag;

    // ---- GAT layers with fused MLP-chain aux blocks (front-placed) ----
    const int aggBlocks = (N / 2 + 3) / 4;   // 2 nodes/wave, 4 waves/block
    const int yMain = N / 128;               // 800
    const ushort_t* curA = x_bf;
    int curK = 96;
    const int mlpGY = R / 128;               // 32
    for (int l = 0; l < 3; l++) {
        // aux GEMM for this launch: MLP layer l
        const ushort_t* xA  = (l == 0) ? rc_bf : (l == 1 ? t1_bf : t2_bf);
        const ushort_t* xBt = (l == 0) ? rW1t : (l == 1 ? rWt2 : rWt3);
        const float*    xB  = (l == 0) ? r_b1 : (l == 1 ? r_b2 : r_b3);
        void*           xC  = (l == 0) ? (void*)t1_bf : (l == 1 ? (void*)t2_bf : (void*)outRoot);
        int xN   = (l == 2) ? 60 : 512;
        int xK   = (l == 0) ? 64 : 512;
        int xGX  = (l == 2) ? 1 : 4;
        int xCnt = xGX * mlpGY;              // 128,128,32
        int xAct = (l == 2) ? 0 : 1;
        int xOutBf = (l == 2) ? 0 : 1;
        int auxY = (xCnt + 1) / 2;           // gridDim.x = 2
        dim3 g1(2, yMain + auxY);
        gemm_gat<<<g1, blk, 0, stream>>>(curA, l == 0 ? Wt0 : (l == 1 ? Wt1 : Wt2),
                                         aS[l], aD[l], h_bf, al_s, al_d,
                                         curK, auxY,
                                         xA, xBt, xB, xC,
                                         xN, xK, xGX, xCnt, xAct, ACT_SLOPE, xOutBf);
        int act = (l < 2) ? 1 : 0;
        gat_agg<<<aggBlocks, blk, 0, stream>>>(h_bf, al_s, al_d, row_ptr,
                                               colArr, bb[l], agg_bf, N,
                                               act, ACT_SLOPE);
        curA = agg_bf;
        curK = 256;
    }

    // ---- rot = h @ fc_w + fc_b ----
    {
        dim3 g(1, N / 128);
        gemm_plain<<<g, blk, 0, stream>>>(agg_bf, fcWt, fc_b, outRot, N, 80, 256,
                                          0, 0.f, 0);
    }
}